// Round 8
// baseline (160.886 us; speedup 1.0000x reference)
//
#include <hip/hip_runtime.h>
#include <hip/hip_bf16.h>

typedef __attribute__((ext_vector_type(4))) float f32x4;
typedef __attribute__((ext_vector_type(4))) unsigned int u32x4;
typedef __attribute__((ext_vector_type(8))) short s16x8;

#define B_  128
#define P_  196
#define E_  2048
#define D_  512
#define A_  512
#define M_  (B_*P_)   // 25088

// global_load_lds: 16B per lane, dest = wave-uniform base + lane*16
typedef __attribute__((address_space(1))) const unsigned int gu32;
typedef __attribute__((address_space(3))) unsigned int lu32;
__device__ __forceinline__ void gl_lds16(const void* g, void* l) {
  __builtin_amdgcn_global_load_lds((gu32*)g, (lu32*)l, 16, 0, 0);
}

#define WAIT_VM6() asm volatile("s_waitcnt vmcnt(6)" ::: "memory")
#define WAIT_VM0() asm volatile("s_waitcnt vmcnt(0)" ::: "memory")
#define WAIT_LGKM0() asm volatile("s_waitcnt lgkmcnt(0)" ::: "memory")

// ---------------------------------------------------------------------------
// Kernel W: transpose + rne-bf16 + PRE-SWIZZLED sub-tile store:
// WeTs[(kt*4+nb)*4096 + ((al*32 + c8*8) ^ ((al&7)<<3)) + j]
//   kt = e>>5, c8 = (e&31)>>3, j = e&7, nb = a>>7, al = a&127.
// Each 4096-short record is the exact 8 KB LDS image of one (K-tile, n-block).
// ---------------------------------------------------------------------------
__global__ void we_conv_kernel(const float* __restrict__ We,
                               unsigned short* __restrict__ WeTs) {
  __shared__ float tile[32][33];
  const int tx = threadIdx.x, ty = threadIdx.y;
  const int a0 = blockIdx.x * 32, e0 = blockIdx.y * 32;
  tile[ty][tx] = We[(e0 + ty) * A_ + a0 + tx];
  __syncthreads();
  const float v = tile[tx][ty];              // = We[e0+tx][a0+ty]
  const unsigned int u = __float_as_uint(v);
  const unsigned short r = (unsigned short)((u + 0x7fffu + ((u >> 16) & 1u)) >> 16);
  const int a = a0 + ty;                     // n-row 0..511
  const int kt = blockIdx.y;                 // e-tile
  const int nb = a >> 7, al = a & 127;
  const int c8 = tx >> 3, j = tx & 7;
  const int dest = ((al * 32 + c8 * 8) ^ ((al & 7) << 3)) + j;
  WeTs[(kt * 4 + nb) * 4096 + dest] = r;
}

// ---------------------------------------------------------------------------
// Kernel A: att2pb[b][a] = decoder_hidden[b] @ Wd + bd[a] + be[a]  (fp32)
// ---------------------------------------------------------------------------
__global__ void att2_kernel(const float* __restrict__ h, const float* __restrict__ Wd,
                            const float* __restrict__ bd, const float* __restrict__ be,
                            float* __restrict__ att2pb) {
  const int b = blockIdx.x;
  const int t = threadIdx.x;  // 256
  __shared__ float hs[D_];
  hs[t] = h[b * D_ + t];
  hs[t + 256] = h[b * D_ + t + 256];
  __syncthreads();
  float a0 = 0.f, a1 = 0.f;
  for (int d = 0; d < D_; ++d) {
    const float hv = hs[d];
    a0 = fmaf(hv, Wd[d * A_ + t], a0);
    a1 = fmaf(hv, Wd[d * A_ + t + 256], a1);
  }
  att2pb[b * A_ + t] = a0 + bd[t] + be[t];
  att2pb[b * A_ + t + 256] = a1 + bd[t + 256] + be[t + 256];
}

// ---------------------------------------------------------------------------
__device__ inline unsigned pk2(float a, float b) {
  union { __hip_bfloat162 h; unsigned u; } cv;
  cv.h = __float22bfloat162_rn(make_float2(a, b));
  return cv.u;
}
__device__ inline u32x4 cvt8(const f32x4 lo, const f32x4 hi) {
  u32x4 r;
  r[0] = pk2(lo[0], lo[1]);
  r[1] = pk2(lo[2], lo[3]);
  r[2] = pk2(hi[0], hi[1]);
  r[3] = pk2(hi[2], hi[3]);
  return r;
}

// ---------------------------------------------------------------------------
// Kernel B v7: 128x128 tile, 256 thr / 4 waves (wave tile 64x64), K=32.
// TRIPLE-buffered, prefetch depth 2, raw s_barrier + counted vmcnt(6)
// (R6-proven discipline). 48 KB LDS -> 3 blocks/CU for cross-block TLP.
// grid = 784 (196 m x 4 n), bijective XCD swizzle (784 = 8*98).
// ---------------------------------------------------------------------------
__launch_bounds__(256, 3)
__global__ void score_kernel(const float* __restrict__ enc,
                             const unsigned short* __restrict__ WeTs,
                             const float* __restrict__ att2pb,
                             const float* __restrict__ Wf,
                             float* __restrict__ att_part) {
  __shared__ unsigned short Ahs[3][4096];   // 3 x 8 KB, swizzled image
  __shared__ unsigned short Bhs[3][4096];   // 3 x 8 KB, swizzled image

  const int orig = blockIdx.x;
  const int bid = (orig & 7) * 98 + (orig >> 3);   // same-XCD chunks of 98
  const int mb = bid >> 2, nb = bid & 3;
  const int m0 = mb * 128;
  const int n0 = nb * 128;

  const int t = threadIdx.x;                // 0..255
  const int lane = t & 63, w = t >> 6;      // 4 waves
  const int wm = (w >> 1) * 64;             // 0 | 64
  const int wn = (w & 1) * 64;              // 0 | 64

  // A staging: rows ar, ar+64; chunk ac (8 f32 = one 16B bf16 chunk)
  const int ar = t >> 2, ac = t & 3;
  const float* aptr = enc + (size_t)(m0 + ar) * E_ + ac * 8;
  const int awz0 = (ar * 32 + ac * 8) ^ ((ar & 7) << 3);
  const int awz1 = ((ar + 64) * 32 + ac * 8) ^ ((ar & 7) << 3);  // same XOR

  // B DMA: per thread 2 chunks of 16B (linear image copy)
  const unsigned short* bsrc = WeTs + (size_t)nb * 4096;   // + kt*16384
  const int doff = t * 8;                   // shorts

  // fragment read offsets
  const int q = lane >> 4, fr = lane & 15;
  const int fx = (fr & 7) << 3;
  int fa[4], fb[4];
#pragma unroll
  for (int i = 0; i < 4; ++i) {
    fa[i] = ((wm + i * 16 + fr) * 32 + q * 8) ^ fx;
    fb[i] = ((wn + i * 16 + fr) * 32 + q * 8) ^ fx;
  }

  const f32x4 zero = {0.f, 0.f, 0.f, 0.f};
  f32x4 acc[4][4];
#pragma unroll
  for (int mi = 0; mi < 4; ++mi)
#pragma unroll
    for (int ni = 0; ni < 4; ++ni) acc[mi][ni] = zero;

  // rotating buffers: *_c = compute (tile t), *_1 = t+1, *_2 = DMA target (t+2)
  unsigned short *bAc = &Ahs[0][0], *bA1 = &Ahs[1][0], *bA2 = &Ahs[2][0];
  unsigned short *bBc = &Bhs[0][0], *bB1 = &Bhs[1][0], *bB2 = &Bhs[2][0];

  f32x4 aC[4], aN[4];   // A(t+1) regs to cvt at end of iter t; A(t+2) in flight

  // ---- prologue: stage tiles 0 and 1
  {
    aC[0] = *(const f32x4*)(aptr);
    aC[1] = *(const f32x4*)(aptr + 4);
    aC[2] = *(const f32x4*)(aptr + 64 * E_);
    aC[3] = *(const f32x4*)(aptr + 64 * E_ + 4);
    gl_lds16(bsrc + doff, bBc + doff);                    // B(0)
    gl_lds16(bsrc + 2048 + doff, bBc + 2048 + doff);
    aN[0] = *(const f32x4*)(aptr + 32);                   // A(1)
    aN[1] = *(const f32x4*)(aptr + 36);
    aN[2] = *(const f32x4*)(aptr + 64 * E_ + 32);
    aN[3] = *(const f32x4*)(aptr + 64 * E_ + 36);
    gl_lds16(bsrc + 16384 + doff, bB1 + doff);            // B(1)
    gl_lds16(bsrc + 16384 + 2048 + doff, bB1 + 2048 + doff);
    *(u32x4*)(bAc + awz0) = cvt8(aC[0], aC[1]);           // A(0) -> LDS
    *(u32x4*)(bAc + awz1) = cvt8(aC[2], aC[3]);
#pragma unroll
    for (int i = 0; i < 4; ++i) aC[i] = aN[i];
    WAIT_VM6();     // B(0) retired (newest 6 = A(1)x4 + B(1)x2)
    WAIT_LGKM0();
    __builtin_amdgcn_s_barrier();
  }

  for (int it = 0; it < 62; ++it) {
    // 1) issue stage(t+2): 4 A-loads + 2 B-DMAs (6 VMEM this iter)
    const int kof = (it + 2) * 32;
    aN[0] = *(const f32x4*)(aptr + kof);
    aN[1] = *(const f32x4*)(aptr + kof + 4);
    aN[2] = *(const f32x4*)(aptr + kof + 64 * E_);
    aN[3] = *(const f32x4*)(aptr + kof + 64 * E_ + 4);
    const unsigned short* sb = bsrc + (size_t)(it + 2) * 16384;
    gl_lds16(sb + doff, bB2 + doff);
    gl_lds16(sb + 2048 + doff, bB2 + 2048 + doff);

    // 2) compute buffer t
    s16x8 fah[4], fbh[4];
#pragma unroll
    for (int i = 0; i < 4; ++i) {
      fah[i] = *(const s16x8*)(bAc + fa[i]);
      fbh[i] = *(const s16x8*)(bBc + fb[i]);
    }
    __builtin_amdgcn_s_setprio(1);
#pragma unroll
    for (int mi = 0; mi < 4; ++mi)
#pragma unroll
      for (int ni = 0; ni < 4; ++ni)
        acc[mi][ni] = __builtin_amdgcn_mfma_f32_16x16x32_bf16(fah[mi], fbh[ni], acc[mi][ni], 0, 0, 0);
    __builtin_amdgcn_s_setprio(0);

    // 3) cvt + write A(t+1) (aC regs retired an iteration ago)
    *(u32x4*)(bA1 + awz0) = cvt8(aC[0], aC[1]);
    *(u32x4*)(bA1 + awz1) = cvt8(aC[2], aC[3]);
#pragma unroll
    for (int i = 0; i < 4; ++i) aC[i] = aN[i];

    // 4) counted drain: this iter's 6 stay in flight; tile t+1 fully resident
    WAIT_VM6();
    WAIT_LGKM0();
    __builtin_amdgcn_s_barrier();

    // 5) rotate
    unsigned short* tmp;
    tmp = bAc; bAc = bA1; bA1 = bA2; bA2 = tmp;
    tmp = bBc; bBc = bB1; bB1 = bB2; bB2 = tmp;
  }

  // ---- it = 62: compute tile 62, cvt+write A(63), full drain
  {
    s16x8 fah[4], fbh[4];
#pragma unroll
    for (int i = 0; i < 4; ++i) {
      fah[i] = *(const s16x8*)(bAc + fa[i]);
      fbh[i] = *(const s16x8*)(bBc + fb[i]);
    }
    __builtin_amdgcn_s_setprio(1);
#pragma unroll
    for (int mi = 0; mi < 4; ++mi)
#pragma unroll
      for (int ni = 0; ni < 4; ++ni)
        acc[mi][ni] = __builtin_amdgcn_mfma_f32_16x16x32_bf16(fah[mi], fbh[ni], acc[mi][ni], 0, 0, 0);
    __builtin_amdgcn_s_setprio(0);
    *(u32x4*)(bA1 + awz0) = cvt8(aC[0], aC[1]);
    *(u32x4*)(bA1 + awz1) = cvt8(aC[2], aC[3]);
    WAIT_VM0();     // B(63) DMA retired
    WAIT_LGKM0();
    __builtin_amdgcn_s_barrier();
  }

  // ---- it = 63: compute tile 63 from bA1/bB1
  {
    s16x8 fah[4], fbh[4];
#pragma unroll
    for (int i = 0; i < 4; ++i) {
      fah[i] = *(const s16x8*)(bA1 + fa[i]);
      fbh[i] = *(const s16x8*)(bB1 + fb[i]);
    }
#pragma unroll
    for (int mi = 0; mi < 4; ++mi)
#pragma unroll
      for (int ni = 0; ni < 4; ++ni)
        acc[mi][ni] = __builtin_amdgcn_mfma_f32_16x16x32_bf16(fah[mi], fbh[ni], acc[mi][ni], 0, 0, 0);
  }

  // epilogue: s = sum_col relu(acc + att2pb[b][col]) * Wf[col], 16-lane reduce
  // C/D layout: col = lane&15, row = (lane>>4)*4 + reg
  const int colL = n0 + wn + fr;
  float wfv[4];
#pragma unroll
  for (int ni = 0; ni < 4; ++ni) wfv[ni] = Wf[colL + ni * 16];
#pragma unroll
  for (int mi = 0; mi < 4; ++mi) {
    const int rowb = m0 + wm + mi * 16 + (q << 2);
#pragma unroll
    for (int r = 0; r < 4; ++r) {
      const int row = rowb + r;
      const int bb = row / P_;
      const float* a2 = att2pb + bb * A_ + colL;
      float s = 0.f;
#pragma unroll
      for (int ni = 0; ni < 4; ++ni)
        s += fmaxf(acc[mi][ni][r] + a2[ni * 16], 0.f) * wfv[ni];
#pragma unroll
      for (int off = 1; off < 16; off <<= 1) s += __shfl_xor(s, off);
      if (fr == 0) att_part[row * 8 + nb * 2 + (w & 1)] = s;
    }
  }
}

// ---------------------------------------------------------------------------
// Kernel C: per (b, e-chunk): sum 8 partials -> softmax over P -> alpha,
// awe[b][e] = sum_p alpha[p] * enc[b][p][e].  grid = B*2, block 256.
// ---------------------------------------------------------------------------
__global__ void softmax_awe_kernel(const float* __restrict__ enc,
                                   const float* __restrict__ att_part,
                                   float* __restrict__ out) {
  const int bid = blockIdx.x;
  const int b = bid >> 1, ch = bid & 1;
  const int t = threadIdx.x;
  __shared__ float sm[256];
  __shared__ float alpha_s[P_];

  float av = -1e30f;
  if (t < P_) {
    const float* apt = att_part + (b * P_ + t) * 8;
    float s = 0.f;
#pragma unroll
    for (int i = 0; i < 8; ++i) s += apt[i];
    av = s;
  }
  sm[t] = av;
  __syncthreads();
  for (int st = 128; st > 0; st >>= 1) {
    if (t < st) sm[t] = fmaxf(sm[t], sm[t + st]);
    __syncthreads();
  }
  const float mx = sm[0];
  __syncthreads();
  float ev = 0.f;
  if (t < P_) ev = __expf(av - mx);
  sm[t] = ev;
  __syncthreads();
  for (int st = 128; st > 0; st >>= 1) {
    if (t < st) sm[t] += sm[t + st];
    __syncthreads();
  }
  const float denom = sm[0];
  const float al = ev / denom;
  if (t < P_) {
    alpha_s[t] = al;
    if (ch == 0) out[B_ * E_ + b * P_ + t] = al;   // alpha output
  }
  __syncthreads();

  const int e0 = ch * 1024 + t * 4;
  const float* ebase = enc + (size_t)b * P_ * E_ + e0;
  f32x4 acc = {0.f, 0.f, 0.f, 0.f};
  for (int p = 0; p < P_; ++p) {
    const f32x4 v = *(const f32x4*)(ebase + (size_t)p * E_);
    const float a = alpha_s[p];
    acc.x += a * v.x; acc.y += a * v.y; acc.z += a * v.z; acc.w += a * v.w;
  }
  *(f32x4*)(out + b * E_ + e0) = acc;
}

// ---------------------------------------------------------------------------
extern "C" void kernel_launch(void* const* d_in, const int* in_sizes, int n_in,
                              void* d_out, int out_size, void* d_ws, size_t ws_size,
                              hipStream_t stream) {
  const float* enc = (const float*)d_in[0];
  const float* h   = (const float*)d_in[1];
  const float* We  = (const float*)d_in[2];
  const float* be  = (const float*)d_in[3];
  const float* Wd  = (const float*)d_in[4];
  const float* bd  = (const float*)d_in[5];
  const float* Wf  = (const float*)d_in[6];
  // d_in[7] = bf: constant shift before softmax -> cancels; unused.
  float* out = (float*)d_out;

  // workspace layout (~3.1 MB)
  float* att2pb = (float*)d_ws;                       // 128*512 f32
  float* att_part = att2pb + B_ * A_;                 // 25088*8 f32
  unsigned short* WeTs = (unsigned short*)(att_part + M_ * 8);  // 64*4*4096 u16

  we_conv_kernel<<<dim3(A_ / 32, E_ / 32), dim3(32, 32), 0, stream>>>(We, WeTs);
  att2_kernel<<<B_, 256, 0, stream>>>(h, Wd, bd, be, att2pb);
  score_kernel<<<(M_ / 128) * 4, 256, 0, stream>>>(enc, WeTs, att2pb, Wf, att_part);
  softmax_awe_kernel<<<B_ * 2, 256, 0, stream>>>(enc, att_part, out);
}